// Round 3
// baseline (155.170 us; speedup 1.0000x reference)
//
#include <hip/hip_runtime.h>
#include <hip/hip_fp16.h>
#include <math.h>

#define NPTS 100000
#define CDIM 64
#define KNN  16

typedef unsigned int uint;
typedef _Float16 f16x8 __attribute__((ext_vector_type(8)));
typedef _Float16 f16x2 __attribute__((ext_vector_type(2)));
typedef float    f32x4 __attribute__((ext_vector_type(4)));
typedef int      i32x4 __attribute__((ext_vector_type(4)));
typedef uint     u32x4 __attribute__((ext_vector_type(4)));
typedef uint     u32x2 __attribute__((ext_vector_type(2)));

// f32 DPP butterfly add: x + x[lane^pattern] (quad_perm ctrls).
template <int CTRL>
__device__ __forceinline__ float dpp_add_f(float x) {
    int yi = __builtin_amdgcn_mov_dpp(__float_as_int(x), CTRL, 0xF, 0xF, true);
    return x + __int_as_float(yi);
}

// v_dot2_f32_f16: c += a.h0*b.h0 + a.h1*b.h1 (f32 accumulate).
__device__ __forceinline__ float dot2acc(uint a, uint b, float c) {
#if __has_builtin(__builtin_amdgcn_fdot2)
    return __builtin_amdgcn_fdot2(__builtin_bit_cast(f16x2, a),
                                  __builtin_bit_cast(f16x2, b), c, false);
#else
    const f16x2 ha = __builtin_bit_cast(f16x2, a);
    const f16x2 hb = __builtin_bit_cast(f16x2, b);
    return c + (float)ha[0] * (float)hb[0] + (float)ha[1] * (float)hb[1];
#endif
}

// v_cvt_pkrtz_f16_f32: pack two f32 into one dword of two f16 (round-to-zero).
__device__ __forceinline__ uint pkrtz(float a, float b) {
    union { __fp16 __attribute__((ext_vector_type(2))) h; uint u; } cv;
    cv.h = __builtin_amdgcn_cvt_pkrtz(a, b);
    return cv.u;
}

// MFMA 16x16x32 f16 fragment maps (symmetric A/B):
//   A[m][k]: m = lane&15, k = quad*8+j      B[k][n]: n = lane&15, k = quad*8+j
//   C/D:     col = lane&15, row = quad*4 + reg
// frag[mat][ct][ks][lane] stores W[k][ct*16+(lane&15)], k = ks*32+quad*8+j.
// As the A operand it acts as W^T: D[row=outch][col=point].

// ---------------------------------------------------------------------------
// Kernel 0: pre-convert W matrices into fragment order (f16).  Wq is
// pre-scaled by 1/sqrt(8)*log2(e) so attention scores feed exp2 directly.
// ---------------------------------------------------------------------------
__global__ __launch_bounds__(256) void pack_w(
    const float* __restrict__ Wq, const float* __restrict__ Wk,
    const float* __restrict__ Wv, const float* __restrict__ Wo,
    __half* __restrict__ frag)
{
    const float* Ws[4] = {Wq, Wk, Wv, Wo};
    const float scale[4] = {0.3535533905932738f * 1.4426950408889634f, 1.f, 1.f, 1.f};
    f16x8* fp = (f16x8*)frag;
    const int e = blockIdx.x * 256 + threadIdx.x;   // 0..2047
    const int lane = e & 63;
    const int ks   = (e >> 6) & 1;
    const int ct   = (e >> 7) & 3;
    const int mat  = e >> 9;
    const int m = lane & 15, quad = lane >> 4;
    const float* W = Ws[mat];
    const float sc = scale[mat];
    f16x8 b;
    #pragma unroll
    for (int j = 0; j < 8; ++j)
        b[j] = (_Float16)(sc * W[(size_t)(ks * 32 + quad * 8 + j) * 64 + ct * 16 + m]);
    fp[e] = b;
}

// feats-side fragment (B operand): B[k][n] = feats[r0 + (lane&15)][quad*8+j].
__device__ __forceinline__ f16x8 load_bfeat(const float* fp, int ks, int quad) {
    const float4 x0 = *(const float4*)(fp + ks * 32 + quad * 8);
    const float4 x1 = *(const float4*)(fp + ks * 32 + quad * 8 + 4);
    f16x8 a;
    a[0] = (_Float16)x0.x; a[1] = (_Float16)x0.y;
    a[2] = (_Float16)x0.z; a[3] = (_Float16)x0.w;
    a[4] = (_Float16)x1.x; a[5] = (_Float16)x1.y;
    a[6] = (_Float16)x1.z; a[7] = (_Float16)x1.w;
    return a;
}

// ---------------------------------------------------------------------------
// Kernel A: k/v projection only (q moved into attn_out).  Operand-swapped
// MFMA (a=W-frag, b=feats-frag): lane's C holds 4 consecutive CHANNELS of
// one point.  TWO tiles per wave to amortize the 16-fragment load.
// ---------------------------------------------------------------------------
__global__ __launch_bounds__(256) void proj_kv(
    const float* __restrict__ feats, const __half* __restrict__ frag,
    uint* __restrict__ kv)
{
    const int wid = blockIdx.x * 4 + (threadIdx.x >> 6);  // 0..3127
    const int lane = threadIdx.x & 63;
    const int m = lane & 15, quad = lane >> 4;

    const f16x8* fp = (const f16x8*)frag;
    f16x8 Wf[2][4][2];                               // Wk, Wv frags
    #pragma unroll
    for (int mat = 0; mat < 2; ++mat)
        #pragma unroll
        for (int ct = 0; ct < 4; ++ct)
            #pragma unroll
            for (int ks = 0; ks < 2; ++ks)
                Wf[mat][ct][ks] = fp[(((mat + 1) * 4 + ct) * 2 + ks) * 64 + lane];

    #pragma unroll
    for (int tt = 0; tt < 2; ++tt) {
        const int tile = wid * 2 + tt;
        if (tile >= NPTS / 16) break;
        const int r0 = tile * 16;
        const float* ap = feats + (size_t)(r0 + m) * 64;
        const f16x8 Bf0 = load_bfeat(ap, 0, quad);
        const f16x8 Bf1 = load_bfeat(ap, 1, quad);
        const size_t pt = (size_t)(r0 + m);

        #pragma unroll
        for (int ct = 0; ct < 4; ++ct) {
            f32x4 ak = {0.f, 0.f, 0.f, 0.f};
            f32x4 av = {0.f, 0.f, 0.f, 0.f};
            ak = __builtin_amdgcn_mfma_f32_16x16x32_f16(Wf[0][ct][0], Bf0, ak, 0, 0, 0);
            ak = __builtin_amdgcn_mfma_f32_16x16x32_f16(Wf[0][ct][1], Bf1, ak, 0, 0, 0);
            av = __builtin_amdgcn_mfma_f32_16x16x32_f16(Wf[1][ct][0], Bf0, av, 0, 0, 0);
            av = __builtin_amdgcn_mfma_f32_16x16x32_f16(Wf[1][ct][1], Bf1, av, 0, 0, 0);

            const int ch = ct * 16 + quad * 4;        // 4 consecutive channels
            uint4 kp;
            kp.x = pkrtz(ak[0], av[0]);
            kp.y = pkrtz(ak[1], av[1]);
            kp.z = pkrtz(ak[2], av[2]);
            kp.w = pkrtz(ak[3], av[3]);
            *(uint4*)(kv + pt * 64 + ch) = kp;
        }
    }
}

// ---------------------------------------------------------------------------
// Kernel B: fused q-projection + kNN attention + output projection.
// Block = 16 points = 4 waves x 4 points.
// Phase 0: q for the block's own 16-point tile via MFMA (wave w -> channel
// quadrant ct=w), routed through 2KB LDS -> no q global round-trip, proj
// shrinks by 1/3, workspace 38.4->25.6MB.
// Phase 1: per lane 4 channels; per neighbor one dwordx4 gather serves a
// 256-B kv row with 16 lanes; score via v_dot2 + ONE dpp xor1; exp2 with
// scale pre-folded into Wq.  (R2 lesson: gather service rate, not issue
// depth, bounds this phase -- R1-style 2x8 batching, no forced staging.)
// Phase 2: full 16-point out-projection MFMA tile.
// ---------------------------------------------------------------------------
__global__ __launch_bounds__(256) void attn_out(
    const float* __restrict__ feats, const uint* __restrict__ kv,
    const int* __restrict__ knn, const __half* __restrict__ frag,
    const float* __restrict__ bo, float* __restrict__ out)
{
    __shared__ uint sQ[16][34];    // q rows as half2 dwords (8B-aligned rows)
    __shared__ uint sO[16][36];    // o rows as half2 dwords
    const int t = threadIdx.x;
    const int lane = t & 63;
    const int w = t >> 6;
    const int l16 = lane & 15;
    const int p4 = lane >> 4;            // 0..3: which of the wave's 4 points
    const int m = lane & 15, quad = lane >> 4;

    const int n0 = blockIdx.x * 16;
    const int n  = n0 + w * 4 + p4;      // uniform within each 16-lane group

    // knn row loads issued first (VMEM latency hides under phase 0).
    const i32x4* kp = (const i32x4*)knn + (size_t)n * 4;
    const i32x4 i0 = __builtin_nontemporal_load(kp);
    const i32x4 i1 = __builtin_nontemporal_load(kp + 1);
    const i32x4 i2 = __builtin_nontemporal_load(kp + 2);
    const i32x4 i3 = __builtin_nontemporal_load(kp + 3);
    const int idx[KNN] = {i0[0], i0[1], i0[2], i0[3], i1[0], i1[1], i1[2], i1[3],
                          i2[0], i2[1], i2[2], i2[3], i3[0], i3[1], i3[2], i3[3]};

    const f16x8* fpb = (const f16x8*)frag;

    // ---- Phase 0: q tile.  Wave w computes out-channels w*16..w*16+15 for
    // all 16 points (D: col=point m, row=quad*4+reg).  Wq pre-scaled by
    // 1/sqrt(8)*log2e so scores feed exp2 directly.
    {
        const f16x8 WfQ0 = fpb[((0 * 4 + w) * 2 + 0) * 64 + lane];
        const f16x8 WfQ1 = fpb[((0 * 4 + w) * 2 + 1) * 64 + lane];
        const float* ap = feats + (size_t)(n0 + m) * 64;
        const f16x8 Bf0 = load_bfeat(ap, 0, quad);
        const f16x8 Bf1 = load_bfeat(ap, 1, quad);
        f32x4 aq = {0.f, 0.f, 0.f, 0.f};
        aq = __builtin_amdgcn_mfma_f32_16x16x32_f16(WfQ0, Bf0, aq, 0, 0, 0);
        aq = __builtin_amdgcn_mfma_f32_16x16x32_f16(WfQ1, Bf1, aq, 0, 0, 0);
        uint2 qp;
        qp.x = pkrtz(aq[0], aq[1]);      // ch w*16+quad*4+0,1 -> dword w*8+quad*2
        qp.y = pkrtz(aq[2], aq[3]);      // ch w*16+quad*4+2,3 -> dword w*8+quad*2+1
        *(uint2*)&sQ[m][w * 8 + quad * 2] = qp;
    }
    __syncthreads();

    // Lane's q: ch 4*l16..4*l16+3 of point n, as two half2 dwords.
    const u32x2 qw = *(const u32x2*)&sQ[w * 4 + p4][2 * l16];

    float ssum = 0.f;
    __half2 acc01 = __float2half2_rn(0.f);
    __half2 acc23 = __float2half2_rn(0.f);

    // ---- Phase 1: two batches of 8 neighbors (8 dwordx4 gathers in flight).
    #pragma unroll
    for (int bb = 0; bb < 2; ++bb) {
        u32x4 u[8];
        #pragma unroll
        for (int i = 0; i < 8; ++i)
            u[i] = *(const u32x4*)(kv + (size_t)idx[bb * 8 + i] * 64 + 4 * l16);
        #pragma unroll
        for (int i = 0; i < 8; ++i) {
            const uint kk01 = __builtin_amdgcn_perm(u[i][1], u[i][0], 0x05040100u);
            const uint kk23 = __builtin_amdgcn_perm(u[i][3], u[i][2], 0x05040100u);
            const uint vv01 = __builtin_amdgcn_perm(u[i][1], u[i][0], 0x07060302u);
            const uint vv23 = __builtin_amdgcn_perm(u[i][3], u[i][2], 0x07060302u);
            float s = dot2acc(qw[1], kk23, dot2acc(qw[0], kk01, 0.f));
            s = dpp_add_f<0xB1>(s);            // + partner lane: full 8-ch head dot
            const float e = __builtin_amdgcn_exp2f(s);
            ssum += e;
            const __half2 w2 = __float2half2_rn(e);
            acc01 = __hfma2(w2, *(const __half2*)&vv01, acc01);
            acc23 = __hfma2(w2, *(const __half2*)&vv23, acc23);
        }
    }

    const float inv = __builtin_amdgcn_rcpf(ssum);
    const __half2 iv = __float2half2_rn(inv);
    acc01 = __hmul2(acc01, iv);
    acc23 = __hmul2(acc23, iv);
    u32x2 ov;
    ov[0] = *(const uint*)&acc01;
    ov[1] = *(const uint*)&acc23;
    *(u32x2*)&sO[w * 4 + p4][2 * l16] = ov;    // dword c of row = ch {2c,2c+1}
    __syncthreads();

    // ---- Phase 2 (swapped): wave w owns out-channel quadrant ct=w.
    // B-frag = o[point = m][ch = quad*8+j] from LDS (f16), full 16 points.
    const f16x8 Wf0 = fpb[((3 * 4 + w) * 2 + 0) * 64 + lane];
    const f16x8 Wf1 = fpb[((3 * 4 + w) * 2 + 1) * 64 + lane];

    const f16x8 Bf  = *(const f16x8*)&sO[m][quad * 4];
    const f16x8 Bf2 = *(const f16x8*)&sO[m][16 + quad * 4];
    f32x4 ac = {0.f, 0.f, 0.f, 0.f};
    ac = __builtin_amdgcn_mfma_f32_16x16x32_f16(Wf0, Bf, ac, 0, 0, 0);
    ac = __builtin_amdgcn_mfma_f32_16x16x32_f16(Wf1, Bf2, ac, 0, 0, 0);

    const int ch = w * 16 + quad * 4;
    const f32x4 bias = *(const f32x4*)(bo + ch);
    f32x4 o;
    o[0] = ac[0] + bias[0]; o[1] = ac[1] + bias[1];
    o[2] = ac[2] + bias[2]; o[3] = ac[3] + bias[3];
    __builtin_nontemporal_store(o, (f32x4*)(out + (size_t)(n0 + m) * 64 + ch));
}

extern "C" void kernel_launch(void* const* d_in, const int* in_sizes, int n_in,
                              void* d_out, int out_size, void* d_ws, size_t ws_size,
                              hipStream_t stream) {
    const float* feats = (const float*)d_in[0];
    const int*   knn   = (const int*)d_in[1];
    const float* Wq    = (const float*)d_in[2];
    const float* Wk    = (const float*)d_in[3];
    const float* Wv    = (const float*)d_in[4];
    const float* Wo    = (const float*)d_in[5];
    const float* bo    = (const float*)d_in[6];
    float* out = (float*)d_out;

    __half* frag = (__half*)d_ws;                                  // 32 KB
    uint*   kvb  = (uint*)((char*)d_ws + 32768);                   // 25.6 MB

    pack_w<<<8, 256, 0, stream>>>(Wq, Wk, Wv, Wo, frag);
    proj_kv<<<782, 256, 0, stream>>>(feats, frag, kvb);            // 2 tiles/wave
    attn_out<<<NPTS / 16, 256, 0, stream>>>(feats, kvb, knn, frag, bo, out);
}

// Round 5
// 153.780 us; speedup vs baseline: 1.0090x; 1.0090x over previous
//
#include <hip/hip_runtime.h>
#include <hip/hip_fp16.h>
#include <math.h>

#define NPTS 100000
#define CDIM 64
#define KNN  16

typedef unsigned int uint;
typedef _Float16 f16x8 __attribute__((ext_vector_type(8)));
typedef _Float16 f16x2 __attribute__((ext_vector_type(2)));
typedef float    f32x4 __attribute__((ext_vector_type(4)));
typedef int      i32x4 __attribute__((ext_vector_type(4)));
typedef uint     u32x4 __attribute__((ext_vector_type(4)));
typedef uint     u32x2 __attribute__((ext_vector_type(2)));

// f32 DPP butterfly add: x + x[lane^pattern] (quad_perm ctrls).
template <int CTRL>
__device__ __forceinline__ float dpp_add_f(float x) {
    int yi = __builtin_amdgcn_mov_dpp(__float_as_int(x), CTRL, 0xF, 0xF, true);
    return x + __int_as_float(yi);
}

// v_dot2_f32_f16: c += a.h0*b.h0 + a.h1*b.h1 (f32 accumulate).
__device__ __forceinline__ float dot2acc(uint a, uint b, float c) {
#if __has_builtin(__builtin_amdgcn_fdot2)
    return __builtin_amdgcn_fdot2(__builtin_bit_cast(f16x2, a),
                                  __builtin_bit_cast(f16x2, b), c, false);
#else
    const f16x2 ha = __builtin_bit_cast(f16x2, a);
    const f16x2 hb = __builtin_bit_cast(f16x2, b);
    return c + (float)ha[0] * (float)hb[0] + (float)ha[1] * (float)hb[1];
#endif
}

// v_cvt_pkrtz_f16_f32: pack two f32 into one dword of two f16 (round-to-zero).
__device__ __forceinline__ uint pkrtz(float a, float b) {
    union { __fp16 __attribute__((ext_vector_type(2))) h; uint u; } cv;
    cv.h = __builtin_amdgcn_cvt_pkrtz(a, b);
    return cv.u;
}

// MFMA 16x16x32 f16 fragment maps (symmetric A/B):
//   A[m][k]: m = lane&15, k = quad*8+j      B[k][n]: n = lane&15, k = quad*8+j
//   C/D:     col = lane&15, row = quad*4 + reg
// frag[mat][ct][ks][lane] stores W[k][ct*16+(lane&15)], k = ks*32+quad*8+j.
// As the A operand it acts as W^T: D[row=outch][col=point].

// ---------------------------------------------------------------------------
// Kernel 0: pre-convert W matrices into fragment order (f16).  Wq is
// pre-scaled by 1/sqrt(8)*log2(e) so attention scores feed exp2 directly.
// ---------------------------------------------------------------------------
__global__ __launch_bounds__(256) void pack_w(
    const float* __restrict__ Wq, const float* __restrict__ Wk,
    const float* __restrict__ Wv, const float* __restrict__ Wo,
    __half* __restrict__ frag)
{
    const float* Ws[4] = {Wq, Wk, Wv, Wo};
    const float scale[4] = {0.3535533905932738f * 1.4426950408889634f, 1.f, 1.f, 1.f};
    f16x8* fp = (f16x8*)frag;
    const int e = blockIdx.x * 256 + threadIdx.x;   // 0..2047
    const int lane = e & 63;
    const int ks   = (e >> 6) & 1;
    const int ct   = (e >> 7) & 3;
    const int mat  = e >> 9;
    const int m = lane & 15, quad = lane >> 4;
    const float* W = Ws[mat];
    const float sc = scale[mat];
    f16x8 b;
    #pragma unroll
    for (int j = 0; j < 8; ++j)
        b[j] = (_Float16)(sc * W[(size_t)(ks * 32 + quad * 8 + j) * 64 + ct * 16 + m]);
    fp[e] = b;
}

// feats-side fragment (B operand): B[k][n] = feats[r0 + (lane&15)][quad*8+j].
__device__ __forceinline__ f16x8 load_bfeat(const float* fp, int ks, int quad) {
    const float4 x0 = *(const float4*)(fp + ks * 32 + quad * 8);
    const float4 x1 = *(const float4*)(fp + ks * 32 + quad * 8 + 4);
    f16x8 a;
    a[0] = (_Float16)x0.x; a[1] = (_Float16)x0.y;
    a[2] = (_Float16)x0.z; a[3] = (_Float16)x0.w;
    a[4] = (_Float16)x1.x; a[5] = (_Float16)x1.y;
    a[6] = (_Float16)x1.z; a[7] = (_Float16)x1.w;
    return a;
}

// ---------------------------------------------------------------------------
// Kernel A: q/k/v projection via MFMA, operand-swapped (a=W-frag, b=feats-
// frag): lane's C holds 4 consecutive CHANNELS of one point.  TWO tiles per
// wave to amortize the 24-fragment load.  Epilogue packs via v_cvt_pkrtz.
// ---------------------------------------------------------------------------
__global__ __launch_bounds__(256) void proj_qkv(
    const float* __restrict__ feats, const __half* __restrict__ frag,
    __half* __restrict__ q, uint* __restrict__ kv)
{
    const int wid = blockIdx.x * 4 + (threadIdx.x >> 6);  // 0..3127
    const int lane = threadIdx.x & 63;
    const int m = lane & 15, quad = lane >> 4;

    const f16x8* fp = (const f16x8*)frag;
    f16x8 Wf[3][4][2];
    #pragma unroll
    for (int mat = 0; mat < 3; ++mat)
        #pragma unroll
        for (int ct = 0; ct < 4; ++ct)
            #pragma unroll
            for (int ks = 0; ks < 2; ++ks)
                Wf[mat][ct][ks] = fp[((mat * 4 + ct) * 2 + ks) * 64 + lane];

    #pragma unroll
    for (int tt = 0; tt < 2; ++tt) {
        const int tile = wid * 2 + tt;
        if (tile >= NPTS / 16) break;
        const int r0 = tile * 16;
        const float* ap = feats + (size_t)(r0 + m) * 64;
        const f16x8 Bf0 = load_bfeat(ap, 0, quad);
        const f16x8 Bf1 = load_bfeat(ap, 1, quad);
        const size_t pt = (size_t)(r0 + m);

        #pragma unroll
        for (int ct = 0; ct < 4; ++ct) {
            f32x4 aq = {0.f, 0.f, 0.f, 0.f};
            f32x4 ak = {0.f, 0.f, 0.f, 0.f};
            f32x4 av = {0.f, 0.f, 0.f, 0.f};
            aq = __builtin_amdgcn_mfma_f32_16x16x32_f16(Wf[0][ct][0], Bf0, aq, 0, 0, 0);
            aq = __builtin_amdgcn_mfma_f32_16x16x32_f16(Wf[0][ct][1], Bf1, aq, 0, 0, 0);
            ak = __builtin_amdgcn_mfma_f32_16x16x32_f16(Wf[1][ct][0], Bf0, ak, 0, 0, 0);
            ak = __builtin_amdgcn_mfma_f32_16x16x32_f16(Wf[1][ct][1], Bf1, ak, 0, 0, 0);
            av = __builtin_amdgcn_mfma_f32_16x16x32_f16(Wf[2][ct][0], Bf0, av, 0, 0, 0);
            av = __builtin_amdgcn_mfma_f32_16x16x32_f16(Wf[2][ct][1], Bf1, av, 0, 0, 0);

            const int ch = ct * 16 + quad * 4;        // 4 consecutive channels
            uint2 qp;
            qp.x = pkrtz(aq[0], aq[1]);
            qp.y = pkrtz(aq[2], aq[3]);
            *(uint2*)(q + pt * 64 + ch) = qp;
            uint4 kp;
            kp.x = pkrtz(ak[0], av[0]);
            kp.y = pkrtz(ak[1], av[1]);
            kp.z = pkrtz(ak[2], av[2]);
            kp.w = pkrtz(ak[3], av[3]);
            *(uint4*)(kv + pt * 64 + ch) = kp;
        }
    }
}

// ---------------------------------------------------------------------------
// Kernel B: fused kNN attention + output projection.  Block = 16 points =
// 4 waves x 4 points; each lane owns 4 channels (l16 = lane&15 -> ch 4*l16..
// 4*l16+3).  Per neighbor one dwordx4 gather serves a 256-B kv row with 16
// lanes; score via v_dot2 + ONE dpp xor1; exp2 with scale pre-folded into
// Wq.  (R0-R2 lesson: attn is pinned at the random-gather service rate --
// VALU halved, occupancy 44-74%, staging depth 8/16 all leave it 56-61us.)
// Phase 2: full 16-point out-projection MFMA tile.
// ---------------------------------------------------------------------------
__global__ __launch_bounds__(256) void attn_out(
    const __half* __restrict__ q, const uint* __restrict__ kv,
    const int* __restrict__ knn, const __half* __restrict__ frag,
    const float* __restrict__ bo, float* __restrict__ out)
{
    __shared__ uint sO[16][36];    // o rows as half2 dwords, stride 36 (16B-align rows)
    const int t = threadIdx.x;
    const int lane = t & 63;
    const int w = t >> 6;
    const int l16 = lane & 15;
    const int p4 = lane >> 5;            // (unused alias kept minimal below)
    const int m = lane & 15, quad = lane >> 4;

    const int n0 = blockIdx.x * 16;
    const int n  = n0 + w * 4 + (lane >> 4);   // uniform within 16-lane group

    // knn row: per-lane VMEM (uniform within 16-lane groups -> one line),
    // streamed once -> non-temporal.
    const i32x4* kp = (const i32x4*)knn + (size_t)n * 4;
    const i32x4 i0 = __builtin_nontemporal_load(kp);
    const i32x4 i1 = __builtin_nontemporal_load(kp + 1);
    const i32x4 i2 = __builtin_nontemporal_load(kp + 2);
    const i32x4 i3 = __builtin_nontemporal_load(kp + 3);
    const int idx[KNN] = {i0[0], i0[1], i0[2], i0[3], i1[0], i1[1], i1[2], i1[3],
                          i2[0], i2[1], i2[2], i2[3], i3[0], i3[1], i3[2], i3[3]};

    // q: lane holds ch 4*l16..4*l16+3 as two half2 dwords (Wq pre-scaled by
    // 1/sqrt(8)*log2e so scores feed exp2 directly).  Streamed -> nt.
    const u32x2 qw = __builtin_nontemporal_load((const u32x2*)q + (size_t)n * 16 + l16);

    float ssum = 0.f;
    __half2 acc01 = __float2half2_rn(0.f);
    __half2 acc23 = __float2half2_rn(0.f);

    // Two batches of 8 neighbors: 8 dwordx4 gathers in flight, then packed
    // score + exp2 + V accumulate.
    #pragma unroll
    for (int bb = 0; bb < 2; ++bb) {
        u32x4 u[8];
        #pragma unroll
        for (int i = 0; i < 8; ++i)
            u[i] = *(const u32x4*)(kv + (size_t)idx[bb * 8 + i] * 64 + 4 * l16);
        #pragma unroll
        for (int i = 0; i < 8; ++i) {
            const uint kk01 = __builtin_amdgcn_perm(u[i][1], u[i][0], 0x05040100u);
            const uint kk23 = __builtin_amdgcn_perm(u[i][3], u[i][2], 0x05040100u);
            const uint vv01 = __builtin_amdgcn_perm(u[i][1], u[i][0], 0x07060302u);
            const uint vv23 = __builtin_amdgcn_perm(u[i][3], u[i][2], 0x07060302u);
            float s = dot2acc(qw[1], kk23, dot2acc(qw[0], kk01, 0.f));
            s = dpp_add_f<0xB1>(s);            // + partner lane: full 8-ch head dot
            const float e = __builtin_amdgcn_exp2f(s);
            ssum += e;
            const __half2 w2 = __float2half2_rn(e);
            acc01 = __hfma2(w2, *(const __half2*)&vv01, acc01);
            acc23 = __hfma2(w2, *(const __half2*)&vv23, acc23);
        }
    }

    const float inv = __builtin_amdgcn_rcpf(ssum);
    const __half2 iv = __float2half2_rn(inv);
    acc01 = __hmul2(acc01, iv);
    acc23 = __hmul2(acc23, iv);
    u32x2 ov;
    ov[0] = *(const uint*)&acc01;
    ov[1] = *(const uint*)&acc23;
    *(u32x2*)&sO[w * 4 + (lane >> 4)][2 * l16] = ov;   // dword c of row = ch {2c,2c+1}
    __syncthreads();

    // Phase 2 (swapped): wave w owns out-channel quadrant ct=w.
    // B-frag = o[point = m][ch = quad*8+j] from LDS (f16), full 16 points.
    const f16x8* fpb = (const f16x8*)frag;
    const f16x8 Wf0 = fpb[((3 * 4 + w) * 2 + 0) * 64 + lane];
    const f16x8 Wf1 = fpb[((3 * 4 + w) * 2 + 1) * 64 + lane];

    const f16x8 Bf  = *(const f16x8*)&sO[m][quad * 4];
    const f16x8 Bf2 = *(const f16x8*)&sO[m][16 + quad * 4];
    f32x4 ac = {0.f, 0.f, 0.f, 0.f};
    ac = __builtin_amdgcn_mfma_f32_16x16x32_f16(Wf0, Bf, ac, 0, 0, 0);
    ac = __builtin_amdgcn_mfma_f32_16x16x32_f16(Wf1, Bf2, ac, 0, 0, 0);

    const int ch = w * 16 + quad * 4;
    const f32x4 bias = *(const f32x4*)(bo + ch);
    f32x4 o;
    o[0] = ac[0] + bias[0]; o[1] = ac[1] + bias[1];
    o[2] = ac[2] + bias[2]; o[3] = ac[3] + bias[3];
    __builtin_nontemporal_store(o, (f32x4*)(out + (size_t)(n0 + m) * 64 + ch));
    (void)p4;
}

extern "C" void kernel_launch(void* const* d_in, const int* in_sizes, int n_in,
                              void* d_out, int out_size, void* d_ws, size_t ws_size,
                              hipStream_t stream) {
    const float* feats = (const float*)d_in[0];
    const int*   knn   = (const int*)d_in[1];
    const float* Wq    = (const float*)d_in[2];
    const float* Wk    = (const float*)d_in[3];
    const float* Wv    = (const float*)d_in[4];
    const float* Wo    = (const float*)d_in[5];
    const float* bo    = (const float*)d_in[6];
    float* out = (float*)d_out;

    __half* frag = (__half*)d_ws;                                  // 32 KB
    __half* q_h  = (__half*)((char*)d_ws + 32768);                 // 12.8 MB
    uint*   kvb  = (uint*)((char*)d_ws + 32768 +
                           (size_t)NPTS * CDIM * sizeof(__half));  // 25.6 MB

    pack_w<<<8, 256, 0, stream>>>(Wq, Wk, Wv, Wo, frag);
    proj_qkv<<<782, 256, 0, stream>>>(feats, frag, q_h, kvb);      // 2 tiles/wave
    attn_out<<<NPTS / 16, 256, 0, stream>>>(q_h, kvb, knn, frag, bo, out);
}